// Round 15
// baseline (228.604 us; speedup 1.0000x reference)
//
#include <hip/hip_runtime.h>
#include <cstdint>
#include <cstddef>

// ---------------------------------------------------------------------------
// GATv2 3-layer forward on MI355X.
//   All GEMM operands fp16 (rel err 5e-4), fp32 accumulate MFMA.
//   k_gemm_mfma : tile 64x256, double-buffered global_load_lds staging,
//                 counted vmcnt(5), 32-bit addrs, XCD-paired block swizzle.
//   k_edge      : 2 nodes/wave, 8 ch/lane, DPP quad_perm score reduce,
//                 packed-fp16 VALU, 2-edge pairwise merge online softmax,
//                 DEPTH-2 SOFTWARE PIPELINE on the row gathers.
// Graph CSR built once (device-wide scan), reused 3x.
// ---------------------------------------------------------------------------

typedef __attribute__((ext_vector_type(8))) _Float16 v8h;
typedef __attribute__((ext_vector_type(2))) _Float16 h2;
typedef __attribute__((ext_vector_type(2))) __fp16 h2r;  // intrinsic ret type
typedef __attribute__((ext_vector_type(4))) float v4f;

__device__ __forceinline__ float lrelu(float v) { return fmaxf(v, 0.2f * v); }
__device__ __forceinline__ float elu1(float v)  { return v > 0.f ? v : expm1f(v); }

__device__ __forceinline__ unsigned short f2h(float f) {
  _Float16 h = (_Float16)f;
  return __builtin_bit_cast(unsigned short, h);
}
__device__ __forceinline__ float h2f(unsigned short s) {
  return (float)__builtin_bit_cast(_Float16, s);
}

__device__ __forceinline__ h2 cvt_pk(float a, float b) {  // f32x2 -> half2
  h2r t = __builtin_amdgcn_cvt_pkrtz(a, b);
  return __builtin_bit_cast(h2, t);
}
__device__ __forceinline__ h2 pk2(float a) { return cvt_pk(a, a); }

// packed lrelu: lrelu(v) = 0.6*v + 0.4*|v|  (|.| is a bitwise AND on the pair)
__device__ __forceinline__ h2 lrelu_pk(h2 v) {
  unsigned int u = __builtin_bit_cast(unsigned int, v) & 0x7FFF7FFFu;
  h2 av = __builtin_bit_cast(h2, u);
  h2 c6 = {(_Float16)0.6f, (_Float16)0.6f};
  h2 c4 = {(_Float16)0.4f, (_Float16)0.4f};
  return v * c6 + av * c4;
}

__device__ __forceinline__ float dot2(h2 a, h2 b, float c) {
#if __has_builtin(__builtin_amdgcn_fdot2)
  return __builtin_amdgcn_fdot2(__builtin_bit_cast(h2r, a),
                                __builtin_bit_cast(h2r, b), c, false);
#else
  return fmaf((float)a[0], (float)b[0], fmaf((float)a[1], (float)b[1], c));
#endif
}

// quad reduce via DPP quad_perm (pure VALU, no LDS pipe)
__device__ __forceinline__ float quad_sum(float p) {
  int t1 = __builtin_amdgcn_update_dpp(0, __float_as_int(p), 0xB1, 0xF, 0xF, true);
  p += __int_as_float(t1);  // xor 1
  int t2 = __builtin_amdgcn_update_dpp(0, __float_as_int(p), 0x4E, 0xF, 0xF, true);
  p += __int_as_float(t2);  // xor 2
  return p;
}

__device__ __forceinline__ void gl_lds16(const void* g, void* l) {
  __builtin_amdgcn_global_load_lds(
      (const __attribute__((address_space(1))) unsigned int*)g,
      (__attribute__((address_space(3))) unsigned int*)l, 16, 0, 0);
}

// ---------------- CSR build ----------------

__global__ void k_count(const int* __restrict__ dst, int* __restrict__ deg, int E) {
  int e = blockIdx.x * blockDim.x + threadIdx.x;
  if (e < E) atomicAdd(&deg[dst[e]], 1);
}

__global__ __launch_bounds__(256) void k_bsum(const int* __restrict__ deg, int n,
                                              int* __restrict__ bsum) {
  __shared__ int red[256];
  int t = threadIdx.x, bid = blockIdx.x;
  int i0 = bid * 1024 + t * 4;
  int s = 0;
  if (i0 + 3 < n) {
    int4 v = *(const int4*)&deg[i0];
    s = v.x + v.y + v.z + v.w;
  } else {
#pragma unroll
    for (int j = 0; j < 4; ++j)
      if (i0 + j < n) s += deg[i0 + j];
  }
  red[t] = s;
  __syncthreads();
  for (int off = 128; off > 0; off >>= 1) {
    if (t < off) red[t] += red[t + off];
    __syncthreads();
  }
  if (t == 0) bsum[bid] = red[0];
}

__global__ __launch_bounds__(256) void k_offsets(const int* __restrict__ deg,
                                                 const int* __restrict__ bsum,
                                                 int nb, int n,
                                                 int* __restrict__ offs,
                                                 int* __restrict__ cursor) {
  __shared__ int sc[256];
  int t = threadIdx.x, bid = blockIdx.x;
  int base = 0;
  for (int b = 0; b < bid; ++b) base += bsum[b];
  int i0 = bid * 1024 + t * 4;
  int v0 = 0, v1 = 0, v2 = 0, v3 = 0;
  if (i0 + 3 < n) {
    int4 v = *(const int4*)&deg[i0];
    v0 = v.x; v1 = v.y; v2 = v.z; v3 = v.w;
  } else {
    if (i0 < n)     v0 = deg[i0];
    if (i0 + 1 < n) v1 = deg[i0 + 1];
    if (i0 + 2 < n) v2 = deg[i0 + 2];
    if (i0 + 3 < n) v3 = deg[i0 + 3];
  }
  int s = v0 + v1 + v2 + v3;
  sc[t] = s;
  __syncthreads();
  for (int off = 1; off < 256; off <<= 1) {
    int x = (t >= off) ? sc[t - off] : 0;
    __syncthreads();
    sc[t] += x;
    __syncthreads();
  }
  int run = base + sc[t] - s;
  int o0 = run, o1 = run + v0, o2 = o1 + v1, o3 = o2 + v2;
  if (i0 + 3 < n) {
    *(int4*)&offs[i0] = make_int4(o0, o1, o2, o3);
    *(int4*)&cursor[i0] = make_int4(o0, o1, o2, o3);
  } else {
    if (i0 < n)     { offs[i0] = o0;     cursor[i0] = o0; }
    if (i0 + 1 < n) { offs[i0 + 1] = o1; cursor[i0 + 1] = o1; }
    if (i0 + 2 < n) { offs[i0 + 2] = o2; cursor[i0 + 2] = o2; }
    if (i0 + 3 < n) { offs[i0 + 3] = o3; cursor[i0 + 3] = o3; }
  }
  if (bid == nb - 1 && t == 255) offs[n] = base + sc[255];
}

__global__ void k_scatter(const int* __restrict__ src, const int* __restrict__ dst,
                          int* __restrict__ cursor, int* __restrict__ csr_src, int E) {
  int e = blockIdx.x * blockDim.x + threadIdx.x;
  if (e < E) {
    int pos = atomicAdd(&cursor[dst[e]], 1);
    csr_src[pos] = src[e];
  }
}

// ---------------- weight transpose+quantize: Bt[n][k] = fp16(W[k][n]) -------

__global__ void k_split(const float* __restrict__ Wl, const float* __restrict__ Wr,
                        int K, int logK, unsigned short* __restrict__ Bt) {
  int idx = blockIdx.x * blockDim.x + threadIdx.x;
  if (idx >= 512 * K) return;
  int n = idx >> logK;
  int k = idx & (K - 1);
  float w = (n < 256) ? Wl[(size_t)k * 256 + n] : Wr[(size_t)k * 256 + (n - 256)];
  Bt[idx] = f2h(w);
}

// ---------------- input quantize: x[N,128] fp32 -> fp16 plane [Npad,128] ----

__global__ void k_quantA(const float* __restrict__ X, int Nreal, int total4,
                         unsigned short* __restrict__ Hh) {
  int idx = blockIdx.x * blockDim.x + threadIdx.x;  // 4 elems each
  if (idx >= total4) return;
  int row = idx >> 5;  // (idx*4)>>7, K=128
  ushort4 uh;
  if (row < Nreal) {
    float4 v = *(const float4*)&X[(size_t)idx * 4];
    uh.x = f2h(v.x); uh.y = f2h(v.y); uh.z = f2h(v.z); uh.w = f2h(v.w);
  } else {
    uh = make_ushort4(0, 0, 0, 0);
  }
  *(ushort4*)&Hh[(size_t)idx * 4] = uh;
}

// ---------------- fp16 MFMA GEMM, tile 64x256, double-buffered --------------
// 1D grid, XCD-paired swizzle: half=(b>>3)&1, rowt=(b&7)|((b>>4)<<3).

__global__ __launch_bounds__(256) void k_gemm_mfma(
    const unsigned short* __restrict__ A_g,  // [Npad,K] fp16
    int Nreal, int K, int nblk,
    const unsigned short* __restrict__ Bt,   // [512,K] fp16 (transposed W)
    const float* __restrict__ bl, const float* __restrict__ br,
    unsigned short* __restrict__ xl_h, unsigned short* __restrict__ xr_h) {
  __shared__ __align__(16) short Ah[2][64 * 32];    // 8 KB
  __shared__ __align__(16) short Bh[2][256 * 32];   // 32 KB

  const int b = blockIdx.x;
  const int half = (b >> 3) & 1;
  const int rowt = (b & 7) | ((b >> 4) << 3);
  if (rowt >= nblk) return;
  const int bm = rowt * 64;
  const int bn = half * 256;

  const int tid = threadIdx.x;
  const int lane = tid & 63;
  const int wid = tid >> 6;
  const int l15 = lane & 15, g = lane >> 4;

  v4f acc[4][4];
#pragma unroll
  for (int m = 0; m < 4; ++m)
#pragma unroll
    for (int n = 0; n < 4; ++n) acc[m][n] = (v4f)(0.f);

  const int arow = tid >> 2, aslot = tid & 3;
  const int aoct = aslot ^ ((arow >> 1) & 3);
  const unsigned gaBase = (unsigned)(bm + arow) * K + aoct * 8;

  auto STAGE = [&](int buf, int k0) {
    gl_lds16(A_g + (gaBase + k0), &Ah[buf][wid * 512]);
#pragma unroll
    for (int it = 0; it < 4; ++it) {
      int task = it * 256 + tid;
      int col = task >> 2, slot = task & 3;
      int oct = slot ^ ((col >> 1) & 3);
      unsigned gb = (unsigned)(bn + col) * K + k0 + oct * 8;
      gl_lds16(Bt + gb, &Bh[buf][it * 2048 + wid * 512]);
    }
  };

  const int nt = K >> 5;
  STAGE(0, 0);
  for (int t = 0; t < nt; ++t) {
    const int cur = t & 1;
    if (t + 1 < nt) {
      STAGE(cur ^ 1, (t + 1) << 5);
      asm volatile("s_waitcnt vmcnt(5)" ::: "memory");  // cur's loads landed
    } else {
      asm volatile("s_waitcnt vmcnt(0)" ::: "memory");
    }
    __builtin_amdgcn_sched_barrier(0);
    __builtin_amdgcn_s_barrier();  // cur buf staged by ALL waves

    v8h a_h[4], b_h[4];
#pragma unroll
    for (int m = 0; m < 4; ++m) {
      int r = m * 16 + l15;
      int s = g ^ ((r >> 1) & 3);
      a_h[m] = *(const v8h*)&Ah[cur][r * 32 + s * 8];
    }
#pragma unroll
    for (int n = 0; n < 4; ++n) {
      int c = wid * 64 + n * 16 + l15;
      int s = g ^ ((c >> 1) & 3);
      b_h[n] = *(const v8h*)&Bh[cur][c * 32 + s * 8];
    }
#pragma unroll
    for (int m = 0; m < 4; ++m)
#pragma unroll
      for (int n = 0; n < 4; ++n)
        acc[m][n] = __builtin_amdgcn_mfma_f32_16x16x32_f16(a_h[m], b_h[n], acc[m][n], 0, 0, 0);
    __builtin_amdgcn_s_barrier();  // cur reads done before re-stage of cur
  }

  // ---- epilogue: per-wave LDS transpose (reuses Bh[0]), fp16 stores ----
  float* scr = (float*)&Bh[0][0] + wid * 320;  // 16 rows x stride 20 floats
  const int erow = lane >> 2, ecq = lane & 3;
  unsigned short* outp = half ? xr_h : xl_h;
  const float* bias = half ? br : bl;
#pragma unroll
  for (int m = 0; m < 4; ++m) {
#pragma unroll
    for (int n = 0; n < 4; ++n) {
#pragma unroll
      for (int r = 0; r < 4; ++r) scr[(g * 4 + r) * 20 + l15] = acc[m][n][r];
      float4 v = *(const float4*)&scr[erow * 20 + ecq * 4];
      int row = bm + m * 16 + erow;
      if (row < Nreal) {
        int col = wid * 64 + n * 16 + ecq * 4;
        float4 bv = *(const float4*)&bias[col];
        ushort4 u;
        u.x = f2h(v.x + bv.x); u.y = f2h(v.y + bv.y);
        u.z = f2h(v.z + bv.z); u.w = f2h(v.w + bv.w);
        *(ushort4*)&outp[(size_t)row * 256 + col] = u;
      }
    }
  }
}

// ---------------- fused GATv2 edge pass (H=8, C=32) -------------------------
// 2 nodes per wave (32 lanes each); lane: q=lane&3, head=(lane>>2)&7.
// Depth-2 pipeline: pair i+1's rows are loaded before pair i's math.

__global__ __launch_bounds__(256) void k_edge(
    const unsigned short* __restrict__ xl_h,  // [N,256] fp16
    const unsigned short* __restrict__ xr_h,  // [N,256] fp16
    const int* __restrict__ offs, const int* __restrict__ csr_src,
    const float* __restrict__ att,   // [8*32]
    const float* __restrict__ bias,  // [256]
    unsigned short* __restrict__ hout,  // [Npad,256] fp16
    int n) {
  int lane = threadIdx.x & 31;              // within 32-lane node group
  int node = blockIdx.x * (blockDim.x >> 5) + (threadIdx.x >> 5);
  if (node >= n) return;

  const unsigned cb = ((unsigned)(lane >> 2) << 5) + ((unsigned)(lane & 3) << 3);
  float4 af0 = *(const float4*)&att[cb];
  float4 af1 = *(const float4*)&att[cb + 4];
  h2 att0 = cvt_pk(af0.x, af0.y), att1 = cvt_pk(af0.z, af0.w);
  h2 att2 = cvt_pk(af1.x, af1.y), att3 = cvt_pk(af1.z, af1.w);
  const unsigned noff = ((unsigned)node << 8) + cb;
  uint4 urx = *(const uint4*)(xr_h + noff);
  h2 xr0 = __builtin_bit_cast(h2, urx.x), xr1 = __builtin_bit_cast(h2, urx.y);
  h2 xr2 = __builtin_bit_cast(h2, urx.z), xr3 = __builtin_bit_cast(h2, urx.w);
  const unsigned short* xlb = xl_h + cb;  // lane-channel base

  auto score = [&](h2 a, h2 b, h2 c, h2 dd) -> float {
    float p = dot2(lrelu_pk(a + xr0), att0, 0.f);
    p = dot2(lrelu_pk(b + xr1), att1, p);
    p = dot2(lrelu_pk(c + xr2), att2, p);
    p = dot2(lrelu_pk(dd + xr3), att3, p);
    return quad_sum(p);
  };

  // self-loop as initial state: m = p_self, d = 1, acc = xl(node)
  uint4 us = *(const uint4*)(xl_h + noff);
  h2 a0 = __builtin_bit_cast(h2, us.x), a1 = __builtin_bit_cast(h2, us.y);
  h2 a2 = __builtin_bit_cast(h2, us.z), a3 = __builtin_bit_cast(h2, us.w);
  float m = score(a0, a1, a2, a3), d = 1.f;

  int e0 = offs[node], e1 = offs[node + 1];
  int e = e0;
  uint4 u1, u2;  // current pair's rows (pipelined)
  if (e + 1 < e1) {
    int j1 = csr_src[e], j2 = csr_src[e + 1];
    u1 = *(const uint4*)(xlb + ((unsigned)j1 << 8));
    u2 = *(const uint4*)(xlb + ((unsigned)j2 << 8));
  }
  for (; e + 1 < e1; e += 2) {
    uint4 un1, un2;
    bool more = (e + 3 < e1);
    if (more) {  // prefetch NEXT pair before current math
      int jn1 = csr_src[e + 2], jn2 = csr_src[e + 3];
      un1 = *(const uint4*)(xlb + ((unsigned)jn1 << 8));
      un2 = *(const uint4*)(xlb + ((unsigned)jn2 << 8));
    }
    h2 x10 = __builtin_bit_cast(h2, u1.x), x11 = __builtin_bit_cast(h2, u1.y);
    h2 x12 = __builtin_bit_cast(h2, u1.z), x13 = __builtin_bit_cast(h2, u1.w);
    h2 x20 = __builtin_bit_cast(h2, u2.x), x21 = __builtin_bit_cast(h2, u2.y);
    h2 x22 = __builtin_bit_cast(h2, u2.z), x23 = __builtin_bit_cast(h2, u2.w);
    float p1 = score(x10, x11, x12, x13);
    float p2 = score(x20, x21, x22, x23);
    // pair-local softmax state
    float m12 = fmaxf(p1, p2);
    float w1 = __expf(p1 - m12), w2 = __expf(p2 - m12);
    float d12 = w1 + w2;
    h2 w1p = pk2(w1), w2p = pk2(w2);
    h2 c0 = x10 * w1p + x20 * w2p;
    h2 c1 = x11 * w1p + x21 * w2p;
    h2 c2 = x12 * w1p + x22 * w2p;
    h2 c3 = x13 * w1p + x23 * w2p;
    // merge into running state (branchless)
    float mN = fmaxf(m, m12);
    float r = __expf(m - mN), r2 = __expf(m12 - mN);
    d = fmaf(d, r, d12 * r2);
    h2 rp = pk2(r), r2p = pk2(r2);
    a0 = a0 * rp + c0 * r2p;
    a1 = a1 * rp + c1 * r2p;
    a2 = a2 * rp + c2 * r2p;
    a3 = a3 * rp + c3 * r2p;
    m = mN;
    if (more) { u1 = un1; u2 = un2; }
  }
  if (e < e1) {  // tail edge
    int j = csr_src[e];
    uint4 u = *(const uint4*)(xlb + ((unsigned)j << 8));
    h2 x0 = __builtin_bit_cast(h2, u.x), x1 = __builtin_bit_cast(h2, u.y);
    h2 x2 = __builtin_bit_cast(h2, u.z), x3 = __builtin_bit_cast(h2, u.w);
    float p1 = score(x0, x1, x2, x3);
    float mN = fmaxf(m, p1);
    float r = __expf(m - mN), w1 = __expf(p1 - mN);
    d = fmaf(d, r, w1);
    h2 rp = pk2(r), w1p = pk2(w1);
    a0 = a0 * rp + x0 * w1p;
    a1 = a1 * rp + x1 * w1p;
    a2 = a2 * rp + x2 * w1p;
    a3 = a3 * rp + x3 * w1p;
  }

  float inv = 1.f / (d + 1e-16f);
  float4 b0 = *(const float4*)&bias[cb];
  float4 b1 = *(const float4*)&bias[cb + 4];
  float o0 = elu1(fmaf((float)a0[0], inv, b0.x));
  float o1 = elu1(fmaf((float)a0[1], inv, b0.y));
  float o2 = elu1(fmaf((float)a1[0], inv, b0.z));
  float o3 = elu1(fmaf((float)a1[1], inv, b0.w));
  float o4 = elu1(fmaf((float)a2[0], inv, b1.x));
  float o5 = elu1(fmaf((float)a2[1], inv, b1.y));
  float o6 = elu1(fmaf((float)a3[0], inv, b1.z));
  float o7 = elu1(fmaf((float)a3[1], inv, b1.w));
  uint4 uo;
  uo.x = (unsigned)f2h(o0) | ((unsigned)f2h(o1) << 16);
  uo.y = (unsigned)f2h(o2) | ((unsigned)f2h(o3) << 16);
  uo.z = (unsigned)f2h(o4) | ((unsigned)f2h(o5) << 16);
  uo.w = (unsigned)f2h(o6) | ((unsigned)f2h(o7) << 16);
  *(uint4*)(hout + noff) = uo;
}

// ---------------- layer 3: skinny linear (256->2 twice), wave per node ------

__global__ __launch_bounds__(256) void k_lin3(
    const unsigned short* __restrict__ hq,
    const float* __restrict__ Wl, const float* __restrict__ bl,
    const float* __restrict__ Wr, const float* __restrict__ br,
    float* __restrict__ xlr3,  // [N,4] = {xl0,xl1,xr0,xr1}
    int n) {
  int lane = threadIdx.x & 63;
  int node = blockIdx.x * (blockDim.x >> 6) + (threadIdx.x >> 6);
  if (node >= n) return;
  ushort4 uh = *(const ushort4*)(hq + (((unsigned)node << 8) + (lane << 2)));
  float hv[4] = {h2f(uh.x), h2f(uh.y), h2f(uh.z), h2f(uh.w)};
  float al0 = 0.f, al1 = 0.f, ar0 = 0.f, ar1 = 0.f;
#pragma unroll
  for (int j = 0; j < 4; ++j) {
    int k = lane * 4 + j;
    al0 = fmaf(hv[j], Wl[k * 2 + 0], al0);
    al1 = fmaf(hv[j], Wl[k * 2 + 1], al1);
    ar0 = fmaf(hv[j], Wr[k * 2 + 0], ar0);
    ar1 = fmaf(hv[j], Wr[k * 2 + 1], ar1);
  }
#pragma unroll
  for (int s = 1; s < 64; s <<= 1) {
    al0 += __shfl_xor(al0, s);
    al1 += __shfl_xor(al1, s);
    ar0 += __shfl_xor(ar0, s);
    ar1 += __shfl_xor(ar1, s);
  }
  if (lane == 0) {
    float4 o = make_float4(al0 + bl[0], al1 + bl[1], ar0 + br[0], ar1 + br[1]);
    *(float4*)&xlr3[(size_t)node * 4] = o;
  }
}

// ---------------- layer 3 edge pass + log_softmax, thread per node ----------

__global__ void k_edge3(const float* __restrict__ xlr3,
                        const int* __restrict__ offs, const int* __restrict__ csr_src,
                        const float* __restrict__ att,  // [2]
                        const float* __restrict__ b,    // [2]
                        float* __restrict__ out, int n) {
  int i = blockIdx.x * blockDim.x + threadIdx.x;
  if (i >= n) return;
  float a0 = att[0], a1 = att[1];
  float xr0 = xlr3[(size_t)i * 4 + 2], xr1 = xlr3[(size_t)i * 4 + 3];
  // self-loop first
  float sl0 = xlr3[(size_t)i * 4 + 0], sl1 = xlr3[(size_t)i * 4 + 1];
  float m = lrelu(sl0 + xr0) * a0 + lrelu(sl1 + xr1) * a1;
  float d = 1.f, ac0 = sl0, ac1 = sl1;
  int e0 = offs[i], e1 = offs[i + 1];
  for (int e = e0; e < e1; ++e) {
    int j = csr_src[e];
    float xl0 = xlr3[(size_t)j * 4 + 0], xl1 = xlr3[(size_t)j * 4 + 1];
    float p = lrelu(xl0 + xr0) * a0 + lrelu(xl1 + xr1) * a1;
    float mN = fmaxf(m, p);
    float r = __expf(m - mN), w = __expf(p - mN);
    d = fmaf(d, r, w);
    ac0 = fmaf(ac0, r, w * xl0);
    ac1 = fmaf(ac1, r, w * xl1);
    m = mN;
  }
  float inv = 1.f / (d + 1e-16f);
  float o0 = fmaf(ac0, inv, b[0]);
  float o1 = fmaf(ac1, inv, b[1]);
  float mx = fmaxf(o0, o1);
  float lse = mx + logf(expf(o0 - mx) + expf(o1 - mx));
  out[(size_t)i * 2 + 0] = o0 - lse;
  out[(size_t)i * 2 + 1] = o1 - lse;
}

// ---------------------------------------------------------------------------

static inline size_t align_up(size_t v, size_t a) { return (v + a - 1) & ~(a - 1); }

extern "C" void kernel_launch(void* const* d_in, const int* in_sizes, int n_in,
                              void* d_out, int out_size, void* d_ws, size_t ws_size,
                              hipStream_t stream) {
  const float* x    = (const float*)d_in[0];
  const int*   ei   = (const int*)d_in[1];
  const float* Wl1  = (const float*)d_in[2];
  const float* bl1  = (const float*)d_in[3];
  const float* Wr1  = (const float*)d_in[4];
  const float* br1  = (const float*)d_in[5];
  const float* att1 = (const float*)d_in[6];
  const float* b1   = (const float*)d_in[7];
  const float* Wl3  = (const float*)d_in[8];
  const float* bl3  = (const float*)d_in[9];
  const float* Wr3  = (const float*)d_in[10];
  const float* br3  = (const float*)d_in[11];
  const float* att3 = (const float*)d_in[12];
  const float* b3   = (const float*)d_in[13];
  const float* Wl2  = (const float*)d_in[14];
  const float* bl2  = (const float*)d_in[15];
  const float* Wr2  = (const float*)d_in[16];
  const float* br2  = (const float*)d_in[17];
  const float* att2 = (const float*)d_in[18];
  const float* b2   = (const float*)d_in[19];

  const int N = in_sizes[0] / 128;  // 50000
  const int E = in_sizes[1] / 2;    // 400000
  const int Npad = ((N + 63) / 64) * 64;  // 50048
  const int* srcp = ei;
  const int* dstp = ei + E;

  // workspace layout
  char* w = (char*)d_ws;
  size_t off = 0;
  int* deg     = (int*)(w + off); off = align_up(off + (size_t)N * 4, 256);
  int* offs    = (int*)(w + off); off = align_up(off + (size_t)(N + 1) * 4, 256);
  int* cursor  = (int*)(w + off); off = align_up(off + (size_t)N * 4, 256);
  int* csr_src = (int*)(w + off); off = align_up(off + (size_t)E * 4, 256);
  int* bsum    = (int*)(w + off); off = align_up(off + (size_t)256 * 4, 256);
  unsigned short* x_h  = (unsigned short*)(w + off); off = align_up(off + (size_t)Npad * 128 * 2, 256);
  unsigned short* h_h  = (unsigned short*)(w + off); off = align_up(off + (size_t)Npad * 256 * 2, 256);
  unsigned short* xlh  = (unsigned short*)(w + off); off = align_up(off + (size_t)N * 256 * 2, 256);
  unsigned short* xrh  = (unsigned short*)(w + off); off = align_up(off + (size_t)N * 256 * 2, 256);
  float* xlr3  = (float*)(w + off); off = align_up(off + (size_t)N * 4 * 4, 256);
  unsigned short* Bt1 = (unsigned short*)(w + off); off = align_up(off + (size_t)512 * 128 * 2, 256);
  unsigned short* Bt2 = (unsigned short*)(w + off); off = align_up(off + (size_t)512 * 256 * 2, 256);
  (void)ws_size;

  const int nb = (N + 1023) / 1024;

  // ---- build CSR (incoming edges per dst), reused by all 3 layers ----
  hipMemsetAsync(deg, 0, (size_t)N * 4, stream);
  k_count<<<(E + 255) / 256, 256, 0, stream>>>(dstp, deg, E);
  k_bsum<<<nb, 256, 0, stream>>>(deg, N, bsum);
  k_offsets<<<nb, 256, 0, stream>>>(deg, bsum, nb, N, offs, cursor);
  k_scatter<<<(E + 255) / 256, 256, 0, stream>>>(srcp, dstp, cursor, csr_src, E);

  // ---- quantize weights (transposed) and x to fp16 ----
  k_split<<<(512 * 128 + 255) / 256, 256, 0, stream>>>(Wl1, Wr1, 128, 7, Bt1);
  k_split<<<(512 * 256 + 255) / 256, 256, 0, stream>>>(Wl3, Wr3, 256, 8, Bt2);
  {
    int total4 = Npad * 128 / 4;
    k_quantA<<<(total4 + 255) / 256, 256, 0, stream>>>(x, N, total4, x_h);
  }
  // zero pad rows of h plane (k_edge writes only rows < N)
  hipMemsetAsync(h_h + (size_t)N * 256, 0, (size_t)(Npad - N) * 256 * 2, stream);

  const int nblk = Npad / 64;                    // 782 row tiles
  const int ggrid = ((nblk + 7) / 8) * 16;       // padded for bijective swizzle
  int nodeBlocks = (N + 7) / 8;  // 8 nodes (32-lane groups) per 256-thread block

  // ---- layer 1: 128 -> 8x32, concat, ELU ----
  k_gemm_mfma<<<ggrid, 256, 0, stream>>>(x_h, N, 128, nblk, Bt1, bl1, br1, xlh, xrh);
  k_edge<<<nodeBlocks, 256, 0, stream>>>(xlh, xrh, offs, csr_src, att1, b1, h_h, N);

  // ---- layer 2: 256 -> 8x32, concat, ELU ----
  k_gemm_mfma<<<ggrid, 256, 0, stream>>>(h_h, N, 256, nblk, Bt2, bl3, br3, xlh, xrh);
  k_edge<<<nodeBlocks, 256, 0, stream>>>(xlh, xrh, offs, csr_src, att3, b3, h_h, N);

  // ---- layer 3: 256 -> 1x2, mean(=identity), log_softmax ----
  k_lin3<<<(N + 3) / 4, 256, 0, stream>>>(h_h, Wl2, bl2, Wr2, br2, xlr3, N);
  k_edge3<<<(N + 255) / 256, 256, 0, stream>>>(xlr3, offs, csr_src, att2, b2,
                                               (float*)d_out, N);
}

// Round 16
// 226.875 us; speedup vs baseline: 1.0076x; 1.0076x over previous
//
#include <hip/hip_runtime.h>
#include <cstdint>
#include <cstddef>

// ---------------------------------------------------------------------------
// GATv2 3-layer forward on MI355X.  (Best-known configuration = R14.)
//   All GEMM operands fp16 (rel err 5e-4), fp32 accumulate MFMA.
//   k_gemm_mfma : tile 64x256, double-buffered global_load_lds staging,
//                 counted vmcnt(5), 32-bit addrs, XCD-paired block swizzle.
//   k_edge      : 2 nodes/wave, 8 ch/lane, DPP quad_perm score reduce,
//                 packed-fp16 VALU, 2-edge pairwise merge online softmax.
// Graph CSR built once (device-wide scan), reused 3x.
// ---------------------------------------------------------------------------

typedef __attribute__((ext_vector_type(8))) _Float16 v8h;
typedef __attribute__((ext_vector_type(2))) _Float16 h2;
typedef __attribute__((ext_vector_type(2))) __fp16 h2r;  // intrinsic ret type
typedef __attribute__((ext_vector_type(4))) float v4f;

__device__ __forceinline__ float lrelu(float v) { return fmaxf(v, 0.2f * v); }
__device__ __forceinline__ float elu1(float v)  { return v > 0.f ? v : expm1f(v); }

__device__ __forceinline__ unsigned short f2h(float f) {
  _Float16 h = (_Float16)f;
  return __builtin_bit_cast(unsigned short, h);
}
__device__ __forceinline__ float h2f(unsigned short s) {
  return (float)__builtin_bit_cast(_Float16, s);
}

__device__ __forceinline__ h2 cvt_pk(float a, float b) {  // f32x2 -> half2
  h2r t = __builtin_amdgcn_cvt_pkrtz(a, b);
  return __builtin_bit_cast(h2, t);
}
__device__ __forceinline__ h2 pk2(float a) { return cvt_pk(a, a); }

// packed lrelu: lrelu(v) = 0.6*v + 0.4*|v|  (|.| is a bitwise AND on the pair)
__device__ __forceinline__ h2 lrelu_pk(h2 v) {
  unsigned int u = __builtin_bit_cast(unsigned int, v) & 0x7FFF7FFFu;
  h2 av = __builtin_bit_cast(h2, u);
  h2 c6 = {(_Float16)0.6f, (_Float16)0.6f};
  h2 c4 = {(_Float16)0.4f, (_Float16)0.4f};
  return v * c6 + av * c4;
}

__device__ __forceinline__ float dot2(h2 a, h2 b, float c) {
#if __has_builtin(__builtin_amdgcn_fdot2)
  return __builtin_amdgcn_fdot2(__builtin_bit_cast(h2r, a),
                                __builtin_bit_cast(h2r, b), c, false);
#else
  return fmaf((float)a[0], (float)b[0], fmaf((float)a[1], (float)b[1], c));
#endif
}

// quad reduce via DPP quad_perm (pure VALU, no LDS pipe)
__device__ __forceinline__ float quad_sum(float p) {
  int t1 = __builtin_amdgcn_update_dpp(0, __float_as_int(p), 0xB1, 0xF, 0xF, true);
  p += __int_as_float(t1);  // xor 1
  int t2 = __builtin_amdgcn_update_dpp(0, __float_as_int(p), 0x4E, 0xF, 0xF, true);
  p += __int_as_float(t2);  // xor 2
  return p;
}

__device__ __forceinline__ void gl_lds16(const void* g, void* l) {
  __builtin_amdgcn_global_load_lds(
      (const __attribute__((address_space(1))) unsigned int*)g,
      (__attribute__((address_space(3))) unsigned int*)l, 16, 0, 0);
}

// ---------------- CSR build ----------------

__global__ void k_count(const int* __restrict__ dst, int* __restrict__ deg, int E) {
  int e = blockIdx.x * blockDim.x + threadIdx.x;
  if (e < E) atomicAdd(&deg[dst[e]], 1);
}

__global__ __launch_bounds__(256) void k_bsum(const int* __restrict__ deg, int n,
                                              int* __restrict__ bsum) {
  __shared__ int red[256];
  int t = threadIdx.x, bid = blockIdx.x;
  int i0 = bid * 1024 + t * 4;
  int s = 0;
  if (i0 + 3 < n) {
    int4 v = *(const int4*)&deg[i0];
    s = v.x + v.y + v.z + v.w;
  } else {
#pragma unroll
    for (int j = 0; j < 4; ++j)
      if (i0 + j < n) s += deg[i0 + j];
  }
  red[t] = s;
  __syncthreads();
  for (int off = 128; off > 0; off >>= 1) {
    if (t < off) red[t] += red[t + off];
    __syncthreads();
  }
  if (t == 0) bsum[bid] = red[0];
}

__global__ __launch_bounds__(256) void k_offsets(const int* __restrict__ deg,
                                                 const int* __restrict__ bsum,
                                                 int nb, int n,
                                                 int* __restrict__ offs,
                                                 int* __restrict__ cursor) {
  __shared__ int sc[256];
  int t = threadIdx.x, bid = blockIdx.x;
  int base = 0;
  for (int b = 0; b < bid; ++b) base += bsum[b];
  int i0 = bid * 1024 + t * 4;
  int v0 = 0, v1 = 0, v2 = 0, v3 = 0;
  if (i0 + 3 < n) {
    int4 v = *(const int4*)&deg[i0];
    v0 = v.x; v1 = v.y; v2 = v.z; v3 = v.w;
  } else {
    if (i0 < n)     v0 = deg[i0];
    if (i0 + 1 < n) v1 = deg[i0 + 1];
    if (i0 + 2 < n) v2 = deg[i0 + 2];
    if (i0 + 3 < n) v3 = deg[i0 + 3];
  }
  int s = v0 + v1 + v2 + v3;
  sc[t] = s;
  __syncthreads();
  for (int off = 1; off < 256; off <<= 1) {
    int x = (t >= off) ? sc[t - off] : 0;
    __syncthreads();
    sc[t] += x;
    __syncthreads();
  }
  int run = base + sc[t] - s;
  int o0 = run, o1 = run + v0, o2 = o1 + v1, o3 = o2 + v2;
  if (i0 + 3 < n) {
    *(int4*)&offs[i0] = make_int4(o0, o1, o2, o3);
    *(int4*)&cursor[i0] = make_int4(o0, o1, o2, o3);
  } else {
    if (i0 < n)     { offs[i0] = o0;     cursor[i0] = o0; }
    if (i0 + 1 < n) { offs[i0 + 1] = o1; cursor[i0 + 1] = o1; }
    if (i0 + 2 < n) { offs[i0 + 2] = o2; cursor[i0 + 2] = o2; }
    if (i0 + 3 < n) { offs[i0 + 3] = o3; cursor[i0 + 3] = o3; }
  }
  if (bid == nb - 1 && t == 255) offs[n] = base + sc[255];
}

__global__ void k_scatter(const int* __restrict__ src, const int* __restrict__ dst,
                          int* __restrict__ cursor, int* __restrict__ csr_src, int E) {
  int e = blockIdx.x * blockDim.x + threadIdx.x;
  if (e < E) {
    int pos = atomicAdd(&cursor[dst[e]], 1);
    csr_src[pos] = src[e];
  }
}

// ---------------- weight transpose+quantize: Bt[n][k] = fp16(W[k][n]) -------

__global__ void k_split(const float* __restrict__ Wl, const float* __restrict__ Wr,
                        int K, int logK, unsigned short* __restrict__ Bt) {
  int idx = blockIdx.x * blockDim.x + threadIdx.x;
  if (idx >= 512 * K) return;
  int n = idx >> logK;
  int k = idx & (K - 1);
  float w = (n < 256) ? Wl[(size_t)k * 256 + n] : Wr[(size_t)k * 256 + (n - 256)];
  Bt[idx] = f2h(w);
}

// ---------------- input quantize: x[N,128] fp32 -> fp16 plane [Npad,128] ----

__global__ void k_quantA(const float* __restrict__ X, int Nreal, int total4,
                         unsigned short* __restrict__ Hh) {
  int idx = blockIdx.x * blockDim.x + threadIdx.x;  // 4 elems each
  if (idx >= total4) return;
  int row = idx >> 5;  // (idx*4)>>7, K=128
  ushort4 uh;
  if (row < Nreal) {
    float4 v = *(const float4*)&X[(size_t)idx * 4];
    uh.x = f2h(v.x); uh.y = f2h(v.y); uh.z = f2h(v.z); uh.w = f2h(v.w);
  } else {
    uh = make_ushort4(0, 0, 0, 0);
  }
  *(ushort4*)&Hh[(size_t)idx * 4] = uh;
}

// ---------------- fp16 MFMA GEMM, tile 64x256, double-buffered --------------
// 1D grid, XCD-paired swizzle: half=(b>>3)&1, rowt=(b&7)|((b>>4)<<3).
// Blocks b and b+8 (same XCD under id%8 round-robin) compute xl/xr of the
// SAME 64-row tile -> second half's A-read hits that XCD's L2.

__global__ __launch_bounds__(256) void k_gemm_mfma(
    const unsigned short* __restrict__ A_g,  // [Npad,K] fp16
    int Nreal, int K, int nblk,
    const unsigned short* __restrict__ Bt,   // [512,K] fp16 (transposed W)
    const float* __restrict__ bl, const float* __restrict__ br,
    unsigned short* __restrict__ xl_h, unsigned short* __restrict__ xr_h) {
  __shared__ __align__(16) short Ah[2][64 * 32];    // 8 KB
  __shared__ __align__(16) short Bh[2][256 * 32];   // 32 KB

  const int b = blockIdx.x;
  const int half = (b >> 3) & 1;
  const int rowt = (b & 7) | ((b >> 4) << 3);
  if (rowt >= nblk) return;
  const int bm = rowt * 64;
  const int bn = half * 256;

  const int tid = threadIdx.x;
  const int lane = tid & 63;
  const int wid = tid >> 6;
  const int l15 = lane & 15, g = lane >> 4;

  v4f acc[4][4];
#pragma unroll
  for (int m = 0; m < 4; ++m)
#pragma unroll
    for (int n = 0; n < 4; ++n) acc[m][n] = (v4f)(0.f);

  const int arow = tid >> 2, aslot = tid & 3;
  const int aoct = aslot ^ ((arow >> 1) & 3);
  const unsigned gaBase = (unsigned)(bm + arow) * K + aoct * 8;

  auto STAGE = [&](int buf, int k0) {
    gl_lds16(A_g + (gaBase + k0), &Ah[buf][wid * 512]);
#pragma unroll
    for (int it = 0; it < 4; ++it) {
      int task = it * 256 + tid;
      int col = task >> 2, slot = task & 3;
      int oct = slot ^ ((col >> 1) & 3);
      unsigned gb = (unsigned)(bn + col) * K + k0 + oct * 8;
      gl_lds16(Bt + gb, &Bh[buf][it * 2048 + wid * 512]);
    }
  };

  const int nt = K >> 5;
  STAGE(0, 0);
  for (int t = 0; t < nt; ++t) {
    const int cur = t & 1;
    if (t + 1 < nt) {
      STAGE(cur ^ 1, (t + 1) << 5);
      asm volatile("s_waitcnt vmcnt(5)" ::: "memory");  // cur's loads landed
    } else {
      asm volatile("s_waitcnt vmcnt(0)" ::: "memory");
    }
    __builtin_amdgcn_sched_barrier(0);
    __builtin_amdgcn_s_barrier();  // cur buf staged by ALL waves

    v8h a_h[4], b_h[4];
#pragma unroll
    for (int m = 0; m < 4; ++m) {
      int r = m * 16 + l15;
      int s = g ^ ((r >> 1) & 3);
      a_h[m] = *(const v8h*)&Ah[cur][r * 32 + s * 8];
    }
#pragma unroll
    for (int n = 0; n < 4; ++n) {
      int c = wid * 64 + n * 16 + l15;
      int s = g ^ ((c >> 1) & 3);
      b_h[n] = *(const v8h*)&Bh[cur][c * 32 + s * 8];
    }
#pragma unroll
    for (int m = 0; m < 4; ++m)
#pragma unroll
      for (int n = 0; n < 4; ++n)
        acc[m][n] = __builtin_amdgcn_mfma_f32_16x16x32_f16(a_h[m], b_h[n], acc[m][n], 0, 0, 0);
    __builtin_amdgcn_s_barrier();  // cur reads done before re-stage of cur
  }

  // ---- epilogue: per-wave LDS transpose (reuses Bh[0]), fp16 stores ----
  float* scr = (float*)&Bh[0][0] + wid * 320;  // 16 rows x stride 20 floats
  const int erow = lane >> 2, ecq = lane & 3;
  unsigned short* outp = half ? xr_h : xl_h;
  const float* bias = half ? br : bl;
#pragma unroll
  for (int m = 0; m < 4; ++m) {
#pragma unroll
    for (int n = 0; n < 4; ++n) {
#pragma unroll
      for (int r = 0; r < 4; ++r) scr[(g * 4 + r) * 20 + l15] = acc[m][n][r];
      float4 v = *(const float4*)&scr[erow * 20 + ecq * 4];
      int row = bm + m * 16 + erow;
      if (row < Nreal) {
        int col = wid * 64 + n * 16 + ecq * 4;
        float4 bv = *(const float4*)&bias[col];
        ushort4 u;
        u.x = f2h(v.x + bv.x); u.y = f2h(v.y + bv.y);
        u.z = f2h(v.z + bv.z); u.w = f2h(v.w + bv.w);
        *(ushort4*)&outp[(size_t)row * 256 + col] = u;
      }
    }
  }
}

// ---------------- fused GATv2 edge pass (H=8, C=32) -------------------------
// 2 nodes per wave (32 lanes each); lane: q=lane&3, head=(lane>>2)&7.
// Each lane owns 8 channels (head*32 + q*8). Score reduce = DPP quad_perm.

__global__ __launch_bounds__(256) void k_edge(
    const unsigned short* __restrict__ xl_h,  // [N,256] fp16
    const unsigned short* __restrict__ xr_h,  // [N,256] fp16
    const int* __restrict__ offs, const int* __restrict__ csr_src,
    const float* __restrict__ att,   // [8*32]
    const float* __restrict__ bias,  // [256]
    unsigned short* __restrict__ hout,  // [Npad,256] fp16
    int n) {
  int lane = threadIdx.x & 31;              // within 32-lane node group
  int node = blockIdx.x * (blockDim.x >> 5) + (threadIdx.x >> 5);
  if (node >= n) return;

  const unsigned cb = ((unsigned)(lane >> 2) << 5) + ((unsigned)(lane & 3) << 3);
  // att / bias for this lane's 8 channels
  float4 af0 = *(const float4*)&att[cb];
  float4 af1 = *(const float4*)&att[cb + 4];
  h2 att0 = cvt_pk(af0.x, af0.y), att1 = cvt_pk(af0.z, af0.w);
  h2 att2 = cvt_pk(af1.x, af1.y), att3 = cvt_pk(af1.z, af1.w);
  const unsigned noff = ((unsigned)node << 8) + cb;
  uint4 urx = *(const uint4*)(xr_h + noff);
  h2 xr0 = __builtin_bit_cast(h2, urx.x), xr1 = __builtin_bit_cast(h2, urx.y);
  h2 xr2 = __builtin_bit_cast(h2, urx.z), xr3 = __builtin_bit_cast(h2, urx.w);
  const unsigned short* xlb = xl_h + cb;  // lane-channel base

  auto score = [&](h2 a, h2 b, h2 c, h2 dd) -> float {
    float p = dot2(lrelu_pk(a + xr0), att0, 0.f);
    p = dot2(lrelu_pk(b + xr1), att1, p);
    p = dot2(lrelu_pk(c + xr2), att2, p);
    p = dot2(lrelu_pk(dd + xr3), att3, p);
    return quad_sum(p);
  };

  // self-loop as initial state: m = p_self, d = 1, acc = xl(node)
  uint4 us = *(const uint4*)(xl_h + noff);
  h2 a0 = __builtin_bit_cast(h2, us.x), a1 = __builtin_bit_cast(h2, us.y);
  h2 a2 = __builtin_bit_cast(h2, us.z), a3 = __builtin_bit_cast(h2, us.w);
  float m = score(a0, a1, a2, a3), d = 1.f;

  int e0 = offs[node], e1 = offs[node + 1];
  int e = e0;
  for (; e + 1 < e1; e += 2) {
    int j1 = csr_src[e], j2 = csr_src[e + 1];
    uint4 u1 = *(const uint4*)(xlb + ((unsigned)j1 << 8));
    uint4 u2 = *(const uint4*)(xlb + ((unsigned)j2 << 8));
    h2 x10 = __builtin_bit_cast(h2, u1.x), x11 = __builtin_bit_cast(h2, u1.y);
    h2 x12 = __builtin_bit_cast(h2, u1.z), x13 = __builtin_bit_cast(h2, u1.w);
    h2 x20 = __builtin_bit_cast(h2, u2.x), x21 = __builtin_bit_cast(h2, u2.y);
    h2 x22 = __builtin_bit_cast(h2, u2.z), x23 = __builtin_bit_cast(h2, u2.w);
    float p1 = score(x10, x11, x12, x13);
    float p2 = score(x20, x21, x22, x23);
    // pair-local softmax state
    float m12 = fmaxf(p1, p2);
    float w1 = __expf(p1 - m12), w2 = __expf(p2 - m12);
    float d12 = w1 + w2;
    h2 w1p = pk2(w1), w2p = pk2(w2);
    h2 c0 = x10 * w1p + x20 * w2p;
    h2 c1 = x11 * w1p + x21 * w2p;
    h2 c2 = x12 * w1p + x22 * w2p;
    h2 c3 = x13 * w1p + x23 * w2p;
    // merge into running state (branchless)
    float mN = fmaxf(m, m12);
    float r = __expf(m - mN), r2 = __expf(m12 - mN);
    d = fmaf(d, r, d12 * r2);
    h2 rp = pk2(r), r2p = pk2(r2);
    a0 = a0 * rp + c0 * r2p;
    a1 = a1 * rp + c1 * r2p;
    a2 = a2 * rp + c2 * r2p;
    a3 = a3 * rp + c3 * r2p;
    m = mN;
  }
  if (e < e1) {  // tail edge
    int j = csr_src[e];
    uint4 u = *(const uint4*)(xlb + ((unsigned)j << 8));
    h2 x0 = __builtin_bit_cast(h2, u.x), x1 = __builtin_bit_cast(h2, u.y);
    h2 x2 = __builtin_bit_cast(h2, u.z), x3 = __builtin_bit_cast(h2, u.w);
    float p1 = score(x0, x1, x2, x3);
    float mN = fmaxf(m, p1);
    float r = __expf(m - mN), w1 = __expf(p1 - mN);
    d = fmaf(d, r, w1);
    h2 rp = pk2(r), w1p = pk2(w1);
    a0 = a0 * rp + x0 * w1p;
    a1 = a1 * rp + x1 * w1p;
    a2 = a2 * rp + x2 * w1p;
    a3 = a3 * rp + x3 * w1p;
  }

  float inv = 1.f / (d + 1e-16f);
  float4 b0 = *(const float4*)&bias[cb];
  float4 b1 = *(const float4*)&bias[cb + 4];
  float o0 = elu1(fmaf((float)a0[0], inv, b0.x));
  float o1 = elu1(fmaf((float)a0[1], inv, b0.y));
  float o2 = elu1(fmaf((float)a1[0], inv, b0.z));
  float o3 = elu1(fmaf((float)a1[1], inv, b0.w));
  float o4 = elu1(fmaf((float)a2[0], inv, b1.x));
  float o5 = elu1(fmaf((float)a2[1], inv, b1.y));
  float o6 = elu1(fmaf((float)a3[0], inv, b1.z));
  float o7 = elu1(fmaf((float)a3[1], inv, b1.w));
  uint4 uo;
  uo.x = (unsigned)f2h(o0) | ((unsigned)f2h(o1) << 16);
  uo.y = (unsigned)f2h(o2) | ((unsigned)f2h(o3) << 16);
  uo.z = (unsigned)f2h(o4) | ((unsigned)f2h(o5) << 16);
  uo.w = (unsigned)f2h(o6) | ((unsigned)f2h(o7) << 16);
  *(uint4*)(hout + noff) = uo;
}

// ---------------- layer 3: skinny linear (256->2 twice), wave per node ------

__global__ __launch_bounds__(256) void k_lin3(
    const unsigned short* __restrict__ hq,
    const float* __restrict__ Wl, const float* __restrict__ bl,
    const float* __restrict__ Wr, const float* __restrict__ br,
    float* __restrict__ xlr3,  // [N,4] = {xl0,xl1,xr0,xr1}
    int n) {
  int lane = threadIdx.x & 63;
  int node = blockIdx.x * (blockDim.x >> 6) + (threadIdx.x >> 6);
  if (node >= n) return;
  ushort4 uh = *(const ushort4*)(hq + (((unsigned)node << 8) + (lane << 2)));
  float hv[4] = {h2f(uh.x), h2f(uh.y), h2f(uh.z), h2f(uh.w)};
  float al0 = 0.f, al1 = 0.f, ar0 = 0.f, ar1 = 0.f;
#pragma unroll
  for (int j = 0; j < 4; ++j) {
    int k = lane * 4 + j;
    al0 = fmaf(hv[j], Wl[k * 2 + 0], al0);
    al1 = fmaf(hv[j], Wl[k * 2 + 1], al1);
    ar0 = fmaf(hv[j], Wr[k * 2 + 0], ar0);
    ar1 = fmaf(hv[j], Wr[k * 2 + 1], ar1);
  }
#pragma unroll
  for (int s = 1; s < 64; s <<= 1) {
    al0 += __shfl_xor(al0, s);
    al1 += __shfl_xor(al1, s);
    ar0 += __shfl_xor(ar0, s);
    ar1 += __shfl_xor(ar1, s);
  }
  if (lane == 0) {
    float4 o = make_float4(al0 + bl[0], al1 + bl[1], ar0 + br[0], ar1 + br[1]);
    *(float4*)&xlr3[(size_t)node * 4] = o;
  }
}

// ---------------- layer 3 edge pass + log_softmax, thread per node ----------

__global__ void k_edge3(const float* __restrict__ xlr3,
                        const int* __restrict__ offs, const int* __restrict__ csr_src,
                        const float* __restrict__ att,  // [2]
                        const float* __restrict__ b,    // [2]
                        float* __restrict__ out, int n) {
  int i = blockIdx.x * blockDim.x + threadIdx.x;
  if (i >= n) return;
  float a0 = att[0], a1 = att[1];
  float xr0 = xlr3[(size_t)i * 4 + 2], xr1 = xlr3[(size_t)i * 4 + 3];
  // self-loop first
  float sl0 = xlr3[(size_t)i * 4 + 0], sl1 = xlr3[(size_t)i * 4 + 1];
  float m = lrelu(sl0 + xr0) * a0 + lrelu(sl1 + xr1) * a1;
  float d = 1.f, ac0 = sl0, ac1 = sl1;
  int e0 = offs[i], e1 = offs[i + 1];
  for (int e = e0; e < e1; ++e) {
    int j = csr_src[e];
    float xl0 = xlr3[(size_t)j * 4 + 0], xl1 = xlr3[(size_t)j * 4 + 1];
    float p = lrelu(xl0 + xr0) * a0 + lrelu(xl1 + xr1) * a1;
    float mN = fmaxf(m, p);
    float r = __expf(m - mN), w = __expf(p - mN);
    d = fmaf(d, r, w);
    ac0 = fmaf(ac0, r, w * xl0);
    ac1 = fmaf(ac1, r, w * xl1);
    m = mN;
  }
  float inv = 1.f / (d + 1e-16f);
  float o0 = fmaf(ac0, inv, b[0]);
  float o1 = fmaf(ac1, inv, b[1]);
  float mx = fmaxf(o0, o1);
  float lse = mx + logf(expf(o0 - mx) + expf(o1 - mx));
  out[(size_t)i * 2 + 0] = o0 - lse;
  out[(size_t)i * 2 + 1] = o1 - lse;
}

// ---------------------------------------------------------------------------

static inline size_t align_up(size_t v, size_t a) { return (v + a - 1) & ~(a - 1); }

extern "C" void kernel_launch(void* const* d_in, const int* in_sizes, int n_in,
                              void* d_out, int out_size, void* d_ws, size_t ws_size,
                              hipStream_t stream) {
  const float* x    = (const float*)d_in[0];
  const int*   ei   = (const int*)d_in[1];
  const float* Wl1  = (const float*)d_in[2];
  const float* bl1  = (const float*)d_in[3];
  const float* Wr1  = (const float*)d_in[4];
  const float* br1  = (const float*)d_in[5];
  const float* att1 = (const float*)d_in[6];
  const float* b1   = (const float*)d_in[7];
  const float* Wl3  = (const float*)d_in[8];
  const float* bl3  = (const float*)d_in[9];
  const float* Wr3  = (const float*)d_in[10];
  const float* br3  = (const float*)d_in[11];
  const float* att3 = (const float*)d_in[12];
  const float* b3   = (const float*)d_in[13];
  const float* Wl2  = (const float*)d_in[14];
  const float* bl2  = (const float*)d_in[15];
  const float* Wr2  = (const float*)d_in[16];
  const float* br2  = (const float*)d_in[17];
  const float* att2 = (const float*)d_in[18];
  const float* b2   = (const float*)d_in[19];

  const int N = in_sizes[0] / 128;  // 50000
  const int E = in_sizes[1] / 2;    // 400000
  const int Npad = ((N + 63) / 64) * 64;  // 50048
  const int* srcp = ei;
  const int* dstp = ei + E;

  // workspace layout
  char* w = (char*)d_ws;
  size_t off = 0;
  int* deg     = (int*)(w + off); off = align_up(off + (size_t)N * 4, 256);
  int* offs    = (int*)(w + off); off = align_up(off + (size_t)(N + 1) * 4, 256);
  int* cursor  = (int*)(w + off); off = align_up(off + (size_t)N * 4, 256);
  int* csr_src = (int*)(w + off); off = align_up(off + (size_t)E * 4, 256);
  int* bsum    = (int*)(w + off); off = align_up(off + (size_t)256 * 4, 256);
  unsigned short* x_h  = (unsigned short*)(w + off); off = align_up(off + (size_t)Npad * 128 * 2, 256);
  unsigned short* h_h  = (unsigned short*)(w + off); off = align_up(off + (size_t)Npad * 256 * 2, 256);
  unsigned short* xlh  = (unsigned short*)(w + off); off = align_up(off + (size_t)N * 256 * 2, 256);
  unsigned short* xrh  = (unsigned short*)(w + off); off = align_up(off + (size_t)N * 256 * 2, 256);
  float* xlr3  = (float*)(w + off); off = align_up(off + (size_t)N * 4 * 4, 256);
  unsigned short* Bt1 = (unsigned short*)(w + off); off = align_up(off + (size_t)512 * 128 * 2, 256);
  unsigned short* Bt2 = (unsigned short*)(w + off); off = align_up(off + (size_t)512 * 256 * 2, 256);
  (void)ws_size;

  const int nb = (N + 1023) / 1024;

  // ---- build CSR (incoming edges per dst), reused by all 3 layers ----
  hipMemsetAsync(deg, 0, (size_t)N * 4, stream);
  k_count<<<(E + 255) / 256, 256, 0, stream>>>(dstp, deg, E);
  k_bsum<<<nb, 256, 0, stream>>>(deg, N, bsum);
  k_offsets<<<nb, 256, 0, stream>>>(deg, bsum, nb, N, offs, cursor);
  k_scatter<<<(E + 255) / 256, 256, 0, stream>>>(srcp, dstp, cursor, csr_src, E);

  // ---- quantize weights (transposed) and x to fp16 ----
  k_split<<<(512 * 128 + 255) / 256, 256, 0, stream>>>(Wl1, Wr1, 128, 7, Bt1);
  k_split<<<(512 * 256 + 255) / 256, 256, 0, stream>>>(Wl3, Wr3, 256, 8, Bt2);
  {
    int total4 = Npad * 128 / 4;
    k_quantA<<<(total4 + 255) / 256, 256, 0, stream>>>(x, N, total4, x_h);
  }
  // zero pad rows of h plane (k_edge writes only rows < N)
  hipMemsetAsync(h_h + (size_t)N * 256, 0, (size_t)(Npad - N) * 256 * 2, stream);

  const int nblk = Npad / 64;                    // 782 row tiles
  const int ggrid = ((nblk + 7) / 8) * 16;       // padded for bijective swizzle
  int nodeBlocks = (N + 7) / 8;  // 8 nodes (32-lane groups) per 256-thread block

  // ---- layer 1: 128 -> 8x32, concat, ELU ----
  k_gemm_mfma<<<ggrid, 256, 0, stream>>>(x_h, N, 128, nblk, Bt1, bl1, br1, xlh, xrh);
  k_edge<<<nodeBlocks, 256, 0, stream>>>(xlh, xrh, offs, csr_src, att1, b1, h_h, N);

  // ---- layer 2: 256 -> 8x32, concat, ELU ----
  k_gemm_mfma<<<ggrid, 256, 0, stream>>>(h_h, N, 256, nblk, Bt2, bl3, br3, xlh, xrh);
  k_edge<<<nodeBlocks, 256, 0, stream>>>(xlh, xrh, offs, csr_src, att3, b3, h_h, N);

  // ---- layer 3: 256 -> 1x2, mean(=identity), log_softmax ----
  k_lin3<<<(N + 3) / 4, 256, 0, stream>>>(h_h, Wl2, bl2, Wr2, br2, xlr3, N);
  k_edge3<<<(N + 255) / 256, 256, 0, stream>>>(xlr3, offs, csr_src, att2, b2,
                                               (float*)d_out, N);
}